// Round 1
// baseline (193.488 us; speedup 1.0000x reference)
//
#include <hip/hip_runtime.h>
#include <hip/hip_fp16.h>
#include <stdint.h>

// Problem: BATCH=4096, LENGTH=128, FEAT=4, RANK=64, 126 mid sites.
#define NSITES 126
#define GROW   72                 // padded row: 72 fp16 = 144 B (64 data + 8 pad)
#define GSITE  (256 * GROW)       // fp16 elems per site tile (36864 B)

typedef _Float16 half8_t __attribute__((ext_vector_type(8)));
typedef float    float4_t __attribute__((ext_vector_type(4)));

// ---------------------------------------------------------------------------
// Prologue: mid_cores fp32 [126][64][256] -> fp16 [126][256][72] (transposed,
// padded rows). Reads coalesced along n; one-time 8.3 MB -> 4.6 MB.
// ---------------------------------------------------------------------------
__global__ __launch_bounds__(256) void repack_g(const float* __restrict__ mid,
                                                _Float16* __restrict__ gt) {
    const int s = blockIdx.x;     // site
    const int n = threadIdx.x;    // 0..255 = (i*64+r)
    const float* src = mid + (size_t)s * 16384 + n;     // stride 256 over l
    _Float16* dst = gt + (size_t)s * GSITE + n * GROW;
    float v[64];
#pragma unroll
    for (int l = 0; l < 64; ++l) v[l] = src[l * 256];
    uint32_t* d32 = (uint32_t*)dst;                      // 4B-aligned (144*n)
#pragma unroll
    for (int l = 0; l < 32; ++l) {
        union { _Float16 h[2]; uint32_t u; } p;
        p.h[0] = (_Float16)v[2 * l];
        p.h[1] = (_Float16)v[2 * l + 1];
        d32[l] = p.u;
    }
}

// async global->LDS, 16B per lane
__device__ __forceinline__ void gload_lds16(const void* g, void* l) {
    __builtin_amdgcn_global_load_lds(
        (const __attribute__((address_space(1))) void*)g,
        (__attribute__((address_space(3))) void*)l, 16, 0, 0);
}

__device__ __forceinline__ void stage_g(const _Float16* gt, int s,
                                        _Float16* dstbase, int w, int lane) {
    const char* src = (const char*)(gt + (size_t)s * GSITE) + w * 9216 + lane * 16;
    char* dst = (char*)dstbase + w * 9216 + lane * 16;
#pragma unroll
    for (int k = 0; k < 9; ++k)
        gload_lds16(src + k * 1024, dst + k * 1024);
}

// ---------------------------------------------------------------------------
// Main: 256 blocks x 256 threads. Block = 16 batches; wave w owns r-range
// [16w,16w+16). Per site: W = V(fp16) @ G(fp16) via 8 MFMA 16x16x32_f16,
// i-combine in-register, v' (fp32) exchanged via LDS (1 barrier/site).
// Per-batch power-of-2 renorm every 8 sites keeps the fp16 cast in range.
// ---------------------------------------------------------------------------
__global__ __launch_bounds__(256) void tt_chain(
    const float* __restrict__ x,      // [4096][128][4]
    const float* __restrict__ first,  // [4][64]
    const float* __restrict__ last,   // [64][4]
    const _Float16* __restrict__ gt,  // [126][256][72] fp16
    float* __restrict__ out) {        // [4096]

    __shared__ _Float16 gbuf[2][GSITE];                  // 2 x 36864 B
    __shared__ float    vbuf[2][16 * 68];                // rows padded: 68 fl
    __shared__ float    xbuf[16 * 516];                  // rows padded: 516 fl
    __shared__ int      eacc[16];

    const int tid  = threadIdx.x;
    const int w    = tid >> 6;          // wave 0..3  -> r-range base 16w
    const int lane = tid & 63;
    const int q    = lane >> 4;         // 0..3
    const int c    = lane & 15;
    const int b0   = blockIdx.x * 16;

    // stage site 0 G (async) as early as possible
    stage_g(gt, 0, gbuf[0], w, lane);

    // stage x: 16 rows x 512 floats (block reads 32KB contiguous)
    {
        const int bb = tid >> 4, seg = tid & 15;
        const float4_t* src = (const float4_t*)(x + (size_t)(b0 + bb) * 512 + seg * 32);
        float4_t* dst = (float4_t*)(xbuf + bb * 516 + seg * 32);
#pragma unroll
        for (int k = 0; k < 8; ++k) dst[k] = src[k];
    }
    if (tid < 16) eacc[tid] = 0;
    __syncthreads();   // xbuf ready (also drains our own site-0 stage)

    // v0[b,r] = sum_i x[b,0,i] * first[i,r]   (fp32, into vbuf[0])
    {
        const int bb = tid >> 4, rq = tid & 15;
        const float xs0 = xbuf[bb * 516 + 0], xs1 = xbuf[bb * 516 + 1];
        const float xs2 = xbuf[bb * 516 + 2], xs3 = xbuf[bb * 516 + 3];
#pragma unroll
        for (int k = 0; k < 4; ++k) {
            const int r = rq * 4 + k;
            vbuf[0][bb * 68 + r] =
                xs0 * first[r] + xs1 * first[64 + r] + xs2 * first[128 + r] + xs3 * first[192 + r];
        }
    }

    for (int s = 0; s < NSITES; ++s) {
        __syncthreads();             // site-s G staged; prev v' visible
        const int p = s & 1;

        // periodic per-batch power-of-2 renormalization of v (fp32 in LDS)
        if ((s & 7) == 0 && s != 0) {
            const int bb = tid >> 4, rq = tid & 15;
            float vv[4];
            float m = 0.f;
#pragma unroll
            for (int k = 0; k < 4; ++k) {
                vv[k] = vbuf[p][bb * 68 + rq * 4 + k];
                m = fmaxf(m, fabsf(vv[k]));
            }
#pragma unroll
            for (int o = 8; o > 0; o >>= 1) m = fmaxf(m, __shfl_xor(m, o, 16));
            int e = 0;
            if (m > 0.f) frexpf(m, &e);          // m = f*2^e, f in [0.5,1)
            const float sc = ldexpf(1.0f, -e);
#pragma unroll
            for (int k = 0; k < 4; ++k) vbuf[p][bb * 68 + rq * 4 + k] = vv[k] * sc;
            if (rq == 0) eacc[bb] += e;
            __syncthreads();
        }

        // prefetch next site's G into the other buffer (overlaps compute)
        if (s + 1 < NSITES) stage_g(gt, s + 1, gbuf[p ^ 1], w, lane);

        // A-fragments: V[b=c][l], l = q*8+j (+32)  -- cast fp32->fp16
        const float* vr = &vbuf[p][c * 68];
        const float4_t a0lo = *(const float4_t*)(vr + q * 8);
        const float4_t a0hi = *(const float4_t*)(vr + q * 8 + 4);
        const float4_t a1lo = *(const float4_t*)(vr + 32 + q * 8);
        const float4_t a1hi = *(const float4_t*)(vr + 32 + q * 8 + 4);
        half8_t af0, af1;
#pragma unroll
        for (int k = 0; k < 4; ++k) {
            af0[k] = (_Float16)a0lo[k]; af0[4 + k] = (_Float16)a0hi[k];
            af1[k] = (_Float16)a1lo[k]; af1[4 + k] = (_Float16)a1hi[k];
        }

        // x scales for b = q*4+jj at site s+1
        float4_t xs[4];
#pragma unroll
        for (int jj = 0; jj < 4; ++jj)
            xs[jj] = *(const float4_t*)(xbuf + (q * 4 + jj) * 516 + (s + 1) * 4);

        // 8 MFMA: acc_i[b,rr] = sum_l V[b,l] * G[l, i*64 + 16w + c]
        const _Float16* gb = gbuf[p];
        float4_t acc[4];
#pragma unroll
        for (int i = 0; i < 4; ++i) {
            const int n = i * 64 + w * 16 + c;
            const half8_t* row = (const half8_t*)(gb + n * GROW);  // 144B rows
            const half8_t bf0 = row[q];        // l = q*8+j
            const half8_t bf1 = row[4 + q];    // l = 32+q*8+j
            float4_t z = {0.f, 0.f, 0.f, 0.f};
            z = __builtin_amdgcn_mfma_f32_16x16x32_f16(af0, bf0, z, 0, 0, 0);
            z = __builtin_amdgcn_mfma_f32_16x16x32_f16(af1, bf1, z, 0, 0, 0);
            acc[i] = z;
        }

        // combine over i and write v' (fp32) to the other v buffer
#pragma unroll
        for (int jj = 0; jj < 4; ++jj) {
            const float vn = xs[jj].x * acc[0][jj] + xs[jj].y * acc[1][jj] +
                             xs[jj].z * acc[2][jj] + xs[jj].w * acc[3][jj];
            vbuf[p ^ 1][(q * 4 + jj) * 68 + w * 16 + c] = vn;
        }
    }

    __syncthreads();   // final v in vbuf[0] (126 is even)

    // out[b] = 2^eacc[b] * sum_r v[b,r] * (sum_i last[r,i]*x[b,127,i])
    {
        const int bb = tid >> 4, rq = tid & 15;
        const float x0 = xbuf[bb * 516 + 508], x1 = xbuf[bb * 516 + 509];
        const float x2 = xbuf[bb * 516 + 510], x3 = xbuf[bb * 516 + 511];
        float dot = 0.f;
#pragma unroll
        for (int k = 0; k < 4; ++k) {
            const int r = rq * 4 + k;
            const float lv = last[r * 4 + 0] * x0 + last[r * 4 + 1] * x1 +
                             last[r * 4 + 2] * x2 + last[r * 4 + 3] * x3;
            dot += lv * vbuf[0][bb * 68 + r];
        }
#pragma unroll
        for (int o = 8; o > 0; o >>= 1) dot += __shfl_xor(dot, o, 16);
        if (rq == 0) out[b0 + bb] = ldexpf(dot, eacc[bb]);
    }
}

extern "C" void kernel_launch(void* const* d_in, const int* in_sizes, int n_in,
                              void* d_out, int out_size, void* d_ws, size_t ws_size,
                              hipStream_t stream) {
    (void)in_sizes; (void)n_in; (void)out_size; (void)ws_size;
    const float* x     = (const float*)d_in[0];
    const float* first = (const float*)d_in[1];
    const float* mid   = (const float*)d_in[2];
    const float* last  = (const float*)d_in[3];
    float* out = (float*)d_out;
    _Float16* gt = (_Float16*)d_ws;   // 126*256*72*2 = 4,644,864 B

    repack_g<<<126, 256, 0, stream>>>(mid, gt);
    tt_chain<<<256, 256, 0, stream>>>(x, first, last, gt, out);
}

// Round 2
// 124.413 us; speedup vs baseline: 1.5552x; 1.5552x over previous
//
#include <hip/hip_runtime.h>
#include <hip/hip_fp16.h>
#include <stdint.h>

// BATCH=4096, LENGTH=128, FEAT=4, RANK=64, 126 mid sites.
#define NSITES 126
#define XPITCH 516                 // xbuf row pitch (floats)
#define VPITCH 68                  // vbuf row pitch (floats)

typedef _Float16 half8_t  __attribute__((ext_vector_type(8)));
typedef float    float4_t __attribute__((ext_vector_type(4)));

// light barrier: LDS-only drain, does NOT wait vmcnt -> register G-prefetch
// stays in flight across sites (the m97-style vmcnt(0)-before-barrier stall
// was ~2000 cyc/site here).
#define LBAR() asm volatile("s_waitcnt lgkmcnt(0)\n\ts_barrier" ::: "memory")

// ---------------------------------------------------------------------------
// Repack mid_cores fp32 [126][64][256] -> fp16 B-fragments in exact lane
// order: frag F = ((i*2+h)*4 + w)*64 + lane, 16B each; element j of frag =
// G[l = 32h + 8q + j][n = i*64 + w*16 + c]  (lane = q*16+c).
// Stage site to LDS coalesced, gather, write coalesced.
// ---------------------------------------------------------------------------
__global__ __launch_bounds__(256) void repack_g(const float* __restrict__ mid,
                                                _Float16* __restrict__ gt) {
    __shared__ float lds[64 * 260];
    const int s = blockIdx.x;
    const int t = threadIdx.x;
    const float* src = mid + (size_t)s * 16384;
#pragma unroll
    for (int k = 0; k < 16; ++k) {
        const int f4 = t + 256 * k;              // float4 index 0..4095
        const int l = f4 >> 6, n0 = (f4 & 63) * 4;
        *(float4_t*)&lds[l * 260 + n0] = *(const float4_t*)&src[f4 * 4];
    }
    __syncthreads();
    half8_t* dst = (half8_t*)gt + (size_t)s * 2048;
#pragma unroll
    for (int m = 0; m < 8; ++m) {
        const int F = t + 256 * m;               // 0..2047
        const int lane = F & 63, w = (F >> 6) & 3, h = (F >> 8) & 1, i = F >> 9;
        const int q = lane >> 4, c = lane & 15;
        const int n = i * 64 + w * 16 + c;
        half8_t o;
#pragma unroll
        for (int j = 0; j < 8; ++j)
            o[j] = (_Float16)lds[(32 * h + 8 * q + j) * 260 + n];
        dst[F] = o;
    }
}

// ---------------------------------------------------------------------------
// Main chain: 256 blocks x 256 threads (1 block/CU, 16 batches/CU).
// Wave w owns r-cols [16w,16w+16). G fragments live in REGISTERS with a
// 3-buffer pipeline loaded straight from global (L2-resident, 32KB/CU/site).
// One light barrier per site for the v' r-exchange through vbuf.
// ---------------------------------------------------------------------------
__global__ __launch_bounds__(256) void tt_chain(
    const float* __restrict__ x,      // [4096][128][4]
    const float* __restrict__ first,  // [4][64]
    const float* __restrict__ last,   // [64][4]
    const _Float16* __restrict__ gt,  // frag-ordered fp16, 2048 half8/site
    float* __restrict__ out) {        // [4096]

    __shared__ float vbuf[2][16 * VPITCH];
    __shared__ float xbuf[16 * XPITCH];
    __shared__ int   eacc[16];

    const int tid  = threadIdx.x;
    const int w    = tid >> 6;
    const int lane = tid & 63;
    const int q    = lane >> 4;
    const int c    = lane & 15;
    const int b0   = blockIdx.x * 16;

    // stage x: 16 rows x 512 floats, coalesced
    {
        const int bb = tid >> 4, seg = tid & 15;
        const float4_t* src = (const float4_t*)(x + (size_t)(b0 + bb) * 512 + seg * 32);
        float4_t* dst = (float4_t*)(xbuf + bb * XPITCH + seg * 32);
#pragma unroll
        for (int k = 0; k < 8; ++k) dst[k] = src[k];
    }
    if (tid < 16) eacc[tid] = 0;
    __syncthreads();

    // v0[b,r] = sum_i x[b,0,i] * first[i,r]
    {
        const int bb = tid >> 4, rq = tid & 15;
        const float xs0 = xbuf[bb * XPITCH + 0], xs1 = xbuf[bb * XPITCH + 1];
        const float xs2 = xbuf[bb * XPITCH + 2], xs3 = xbuf[bb * XPITCH + 3];
#pragma unroll
        for (int k = 0; k < 4; ++k) {
            const int r = rq * 4 + k;
            vbuf[0][bb * VPITCH + r] =
                xs0 * first[r] + xs1 * first[64 + r] + xs2 * first[128 + r] + xs3 * first[192 + r];
        }
    }

    // register G pipeline
    half8_t F0[8], F1[8], F2[8];
    const half8_t* gb = (const half8_t*)gt + w * 64 + lane;
    auto LOAD = [&](int s, half8_t* F) {
        const half8_t* p = gb + (size_t)s * 2048;
#pragma unroll
        for (int ih = 0; ih < 8; ++ih) F[ih] = p[ih * 256];
    };
    LOAD(0, F0);
    LOAD(1, F1);
    LBAR();   // vbuf[0] visible

    auto STEP = [&](int s, half8_t* F) {
        const int p = s & 1;
        const float* vr = &vbuf[p][c * VPITCH];
        float4_t a0lo = *(const float4_t*)(vr + q * 8);
        float4_t a0hi = *(const float4_t*)(vr + q * 8 + 4);
        float4_t a1lo = *(const float4_t*)(vr + 32 + q * 8);
        float4_t a1hi = *(const float4_t*)(vr + 32 + q * 8 + 4);

        // wave-local per-batch power-of-2 renorm every 8 sites (no barrier:
        // every wave reads the full l-range for its b=c, so the max over l
        // needs only shfl_xor 16/32; all waves compute identical e).
        if ((s & 7) == 0 && s != 0) {
            float m = 0.f;
#pragma unroll
            for (int k = 0; k < 4; ++k) {
                m = fmaxf(m, fabsf(a0lo[k])); m = fmaxf(m, fabsf(a0hi[k]));
                m = fmaxf(m, fabsf(a1lo[k])); m = fmaxf(m, fabsf(a1hi[k]));
            }
            m = fmaxf(m, __shfl_xor(m, 16));
            m = fmaxf(m, __shfl_xor(m, 32));
            int e = 0;
            if (m > 0.f) frexpf(m, &e);
            const float sc = ldexpf(1.0f, -e);
#pragma unroll
            for (int k = 0; k < 4; ++k) {
                a0lo[k] *= sc; a0hi[k] *= sc; a1lo[k] *= sc; a1hi[k] *= sc;
            }
            if (tid < 16) eacc[tid] += e;   // wave 0, q=0: lane==c==batch
        }

        half8_t af0, af1;
#pragma unroll
        for (int k = 0; k < 4; ++k) {
            af0[k] = (_Float16)a0lo[k]; af0[4 + k] = (_Float16)a0hi[k];
            af1[k] = (_Float16)a1lo[k]; af1[4 + k] = (_Float16)a1hi[k];
        }

        float4_t xs[4];
#pragma unroll
        for (int jj = 0; jj < 4; ++jj)
            xs[jj] = *(const float4_t*)(xbuf + (q * 4 + jj) * XPITCH + (s + 1) * 4);

        float4_t acc[4];
#pragma unroll
        for (int i = 0; i < 4; ++i) {
            float4_t z = {0.f, 0.f, 0.f, 0.f};
            z = __builtin_amdgcn_mfma_f32_16x16x32_f16(af0, F[i * 2 + 0], z, 0, 0, 0);
            z = __builtin_amdgcn_mfma_f32_16x16x32_f16(af1, F[i * 2 + 1], z, 0, 0, 0);
            acc[i] = z;
        }

#pragma unroll
        for (int jj = 0; jj < 4; ++jj) {
            const float vn = xs[jj].x * acc[0][jj] + xs[jj].y * acc[1][jj] +
                             xs[jj].z * acc[2][jj] + xs[jj].w * acc[3][jj];
            vbuf[p ^ 1][(q * 4 + jj) * VPITCH + w * 16 + c] = vn;
        }
        LBAR();
    };

    for (int s = 0; s < NSITES; s += 3) {
        const int s2 = (s + 2 < NSITES) ? s + 2 : NSITES - 1;
        const int s3 = (s + 3 < NSITES) ? s + 3 : NSITES - 1;
        const int s4 = (s + 4 < NSITES) ? s + 4 : NSITES - 1;
        LOAD(s2, F2);
        STEP(s, F0);
        LOAD(s3, F0);
        STEP(s + 1, F1);
        LOAD(s4, F1);
        STEP(s + 2, F2);
    }

    // final v in vbuf[0] (126 even); out[b] = 2^eacc * sum_r v*last_vec
    {
        const int bb = tid >> 4, rq = tid & 15;
        const float x0 = xbuf[bb * XPITCH + 508], x1 = xbuf[bb * XPITCH + 509];
        const float x2 = xbuf[bb * XPITCH + 510], x3 = xbuf[bb * XPITCH + 511];
        float dot = 0.f;
#pragma unroll
        for (int k = 0; k < 4; ++k) {
            const int r = rq * 4 + k;
            const float lv = last[r * 4 + 0] * x0 + last[r * 4 + 1] * x1 +
                             last[r * 4 + 2] * x2 + last[r * 4 + 3] * x3;
            dot += lv * vbuf[0][bb * VPITCH + r];
        }
#pragma unroll
        for (int o = 8; o > 0; o >>= 1) dot += __shfl_xor(dot, o, 16);
        if (rq == 0) out[b0 + bb] = ldexpf(dot, eacc[bb]);
    }
}

extern "C" void kernel_launch(void* const* d_in, const int* in_sizes, int n_in,
                              void* d_out, int out_size, void* d_ws, size_t ws_size,
                              hipStream_t stream) {
    (void)in_sizes; (void)n_in; (void)out_size; (void)ws_size;
    const float* x     = (const float*)d_in[0];
    const float* first = (const float*)d_in[1];
    const float* mid   = (const float*)d_in[2];
    const float* last  = (const float*)d_in[3];
    float* out = (float*)d_out;
    _Float16* gt = (_Float16*)d_ws;   // 126*2048*16 B = 4,128,768 B

    repack_g<<<126, 256, 0, stream>>>(mid, gt);
    tt_chain<<<256, 256, 0, stream>>>(x, first, last, gt, out);
}